// Round 3
// baseline (87.554 us; speedup 1.0000x reference)
//
#include <hip/hip_runtime.h>

// B=256, IN_F=512, K_INT=75, OUT_F=64
// ws layout: Mt[o][k][b] fp32 = 64*75*256*4 = 4,915,200 B, then xT[512][256] = 524,288 B.

// ---------- kernel 0: transpose x[256][512] -> xT[512][256] ----------
__global__ __launch_bounds__(256) void xt_kernel(const float* __restrict__ x,
                                                 float* __restrict__ xT) {
  __shared__ float t[32][33];
  const int bt = blockIdx.x;        // b-tile 0..7
  const int ft = blockIdx.y;        // f-tile 0..15
  const int c = threadIdx.x & 31;
  const int rg = threadIdx.x >> 5;  // 0..7
#pragma unroll
  for (int s = 0; s < 4; ++s) {
    const int r = (rg << 2) + s;
    t[r][c] = x[(bt * 32 + r) * 512 + ft * 32 + c];   // coalesced
  }
  __syncthreads();
#pragma unroll
  for (int s = 0; s < 4; ++s) {
    const int rr = (rg << 2) + s;
    xT[(ft * 32 + rr) * 256 + bt * 32 + c] = t[c][rr]; // coalesced, LDS conflict-free (33 pad)
  }
}

// ---------- kernel 1: Mt[o][kc][b] = sum_f x[b][f] * T[f][kc][o] ----------
// Block: one kc, all 64 o, 64 b. Thread: 4 o x 4 b. Double-buffered LDS staging.
__global__ __launch_bounds__(256) void md_gemm(const float* __restrict__ xT,
                                               const float* __restrict__ T,
                                               float* __restrict__ Mt) {
  // XCD-swizzle decode: blocks sharing kc differ by 8 in id -> same XCD (round-robin)
  const int id = blockIdx.x;
  const int r = id & 7;
  const int m = id >> 3;
  const int bc = m & 3;
  const int kc = (m >> 2) * 8 + r;
  if (kc >= 75) return;
  const int b0 = bc << 6;
  const int tid = threadIdx.x;
  const int bq = tid & 15;   // b-quad: b = b0 + 4*bq + e
  const int og = tid >> 4;   // o-quad: o = 4*og + d

  __shared__ float4 xs[2][1024];  // [f_local 64][b-quad 16]
  __shared__ float4 ts[2][1024];  // [f_local 64][o-quad 16]

  const float4* xT4 = reinterpret_cast<const float4*>(xT);
  const float4* T4 = reinterpret_cast<const float4*>(T);

  float4 rx[4], rt[4];
  float acc[4][4];
#pragma unroll
  for (int d = 0; d < 4; ++d)
#pragma unroll
    for (int e = 0; e < 4; ++e) acc[d][e] = 0.0f;

  auto LOAD = [&](int fc) {
#pragma unroll
    for (int h = 0; h < 4; ++h) {
      const int idx = tid + (h << 8);      // 0..1023
      const int ff = idx >> 4, q = idx & 15;
      rx[h] = xT4[(fc * 64 + ff) * 64 + (b0 >> 2) + q];      // xT row = 64 quads
      rt[h] = T4[(fc * 64 + ff) * 1200 + kc * 16 + q];       // T row = 1200 quads
    }
  };
  auto WRITE = [&](int buf) {
#pragma unroll
    for (int h = 0; h < 4; ++h) {
      const int idx = tid + (h << 8);
      xs[buf][idx] = rx[h];
      ts[buf][idx] = rt[h];
    }
  };

  LOAD(0);
  WRITE(0);
  __syncthreads();

  for (int fc = 0; fc < 8; ++fc) {
    if (fc < 7) LOAD(fc + 1);            // in-flight during compute
    const int buf = fc & 1;
#pragma unroll 8
    for (int ff = 0; ff < 64; ++ff) {
      const float4 xa = xs[buf][(ff << 4) + bq];   // 16 distinct quads, 4-way bcast
      const float4 tb = ts[buf][(ff << 4) + og];   // 4 distinct quads, 16-way bcast
      acc[0][0] += tb.x * xa.x; acc[0][1] += tb.x * xa.y; acc[0][2] += tb.x * xa.z; acc[0][3] += tb.x * xa.w;
      acc[1][0] += tb.y * xa.x; acc[1][1] += tb.y * xa.y; acc[1][2] += tb.y * xa.z; acc[1][3] += tb.y * xa.w;
      acc[2][0] += tb.z * xa.x; acc[2][1] += tb.z * xa.y; acc[2][2] += tb.z * xa.z; acc[2][3] += tb.z * xa.w;
      acc[3][0] += tb.w * xa.x; acc[3][1] += tb.w * xa.y; acc[3][2] += tb.w * xa.z; acc[3][3] += tb.w * xa.w;
    }
    if (fc < 7) {
      __syncthreads();
      WRITE((fc + 1) & 1);
      __syncthreads();
    }
  }

  // store: float4 over e -> fully coalesced (4 o-rows x 256 B per inst)
#pragma unroll
  for (int d = 0; d < 4; ++d) {
    const int o = (og << 2) + d;
    const float4 v = make_float4(acc[d][0], acc[d][1], acc[d][2], acc[d][3]);
    *reinterpret_cast<float4*>(Mt + o * 19200 + kc * 256 + b0 + (bq << 2)) = v;
  }
}

// ---------- kernel 2: pairwise L1 + exp + row-sum ----------
// Block: (o, 32-i chunk). LDS = Mo[k][b] staged untransposed (contiguous copy).
// Thread (io, jg): i = ibase+io, 32 j's; k-outer accumulation, float4 over j.
__global__ __launch_bounds__(256) void md_pair(const float* __restrict__ Mt,
                                               float* __restrict__ out) {
  const int o = blockIdx.x;            // 0..63
  const int ibase = blockIdx.y << 5;   // 32 i per block
  const int tid = threadIdx.x;

  __shared__ float smem[75 * 256];     // 76,800 B

  // contiguous copy: 4800 float4, coalesced global + throughput-optimal LDS writes
  {
    const float4* src4 = reinterpret_cast<const float4*>(Mt + o * 19200);
    float4* dst4 = reinterpret_cast<float4*>(smem);
#pragma unroll
    for (int t = 0; t < 19; ++t) {
      const int idx = tid + (t << 8);
      if (idx < 4800) dst4[idx] = src4[idx];
    }
  }
  __syncthreads();

  const int io = tid & 31;
  const int jg = tid >> 5;             // 0..7 -> j in [32*jg, 32*jg+32)
  const int i = ibase + io;

  float d[32];
#pragma unroll
  for (int q = 0; q < 32; ++q) d[q] = 0.0f;

  for (int k = 0; k < 75; ++k) {
    const float mi = smem[k * 256 + i];                     // 32 consecutive, 2x bcast
    const float4* row4 = reinterpret_cast<const float4*>(smem + k * 256) + (jg << 3);
#pragma unroll
    for (int q = 0; q < 8; ++q) {
      const float4 v = row4[q];                             // 2 distinct addrs/wave: bcast
      d[4 * q + 0] += __builtin_fabsf(v.x - mi);
      d[4 * q + 1] += __builtin_fabsf(v.y - mi);
      d[4 * q + 2] += __builtin_fabsf(v.z - mi);
      d[4 * q + 3] += __builtin_fabsf(v.w - mi);
    }
  }

  float s = 0.0f;
#pragma unroll
  for (int q = 0; q < 32; ++q) s += __expf(-d[q]);          // j==i: exp(0)=1 cancels -1

  __syncthreads();                     // all k-loop reads done before smem reuse
  float* red = smem;                   // red[io*9 + jg], stride 9 -> conflict-free
  red[io * 9 + jg] = s;
  __syncthreads();
  if (tid < 32) {
    float acc = 0.0f;
#pragma unroll
    for (int g = 0; g < 8; ++g) acc += red[tid * 9 + g];
    out[(ibase + tid) * 64 + o] = acc - 1.0f;
  }
}

extern "C" void kernel_launch(void* const* d_in, const int* in_sizes, int n_in,
                              void* d_out, int out_size, void* d_ws, size_t ws_size,
                              hipStream_t stream) {
  const float* x = (const float*)d_in[0];   // [256,512]
  const float* T = (const float*)d_in[1];   // [512,75,64]
  float* out = (float*)d_out;               // [256,64]
  float* Mt = (float*)d_ws;                 // [64][75][256]
  float* xT = Mt + 64 * 75 * 256;           // [512][256]

  xt_kernel<<<dim3(8, 16), 256, 0, stream>>>(x, xT);
  md_gemm<<<320, 256, 0, stream>>>(xT, T, Mt);   // 20 dead blocks (kc>=75) early-return
  md_pair<<<dim3(64, 8), 256, 0, stream>>>(Mt, out);
}